// Round 1
// baseline (48.046 us; speedup 1.0000x reference)
//
#include <hip/hip_runtime.h>
#include <hip/hip_bf16.h>

// DomainBatchNorm: out[b,f] = x[b,f] * scale[d(b),f] + shift[d(b),f]
//   scale = gamma * rsqrt(var + eps);  shift = beta - mean * scale
// Shapes: x [B,1024] f32, mask [B,8] f32 one-hot, params [8,1024] f32 each.
// Memory-bound: ~257 MB HBM traffic -> ~41 us floor at 6.3 TB/s.

#define F_DIM 1024
#define D_DIM 8
#define EPSV  1e-5f

__global__ __launch_bounds__(256) void DomainBatchNorm_kernel(
    const float4* __restrict__ x,       // [B, F/4]
    const float*  __restrict__ mask,    // [B, D]
    const float4* __restrict__ gammas,  // [D, F/4]
    const float4* __restrict__ betas,
    const float4* __restrict__ means,
    const float4* __restrict__ vars,
    float4* __restrict__ out)           // [B, F/4]
{
    const int row = blockIdx.x;
    const int t   = threadIdx.x;        // 0..255, one float4 each (F=1024)

    // Resolve this row's domain: mask is exact one-hot, so exactly one
    // thread writes sdom. Cheap vs. the 4 KB row traffic.
    __shared__ int sdom;
    if (t < D_DIM) {
        if (mask[(size_t)row * D_DIM + t] > 0.5f) sdom = t;
    }
    __syncthreads();
    const int d = sdom;

    const size_t prm = (size_t)d * (F_DIM / 4) + t;   // param index (float4 units)
    const size_t idx = (size_t)row * (F_DIM / 4) + t; // row-major x/out index

    const float4 g  = gammas[prm];
    const float4 bt = betas[prm];
    const float4 mu = means[prm];
    const float4 vr = vars[prm];
    const float4 xv = x[idx];

    float4 o;
    {
        float s;
        s   = g.x * rsqrtf(vr.x + EPSV); o.x = fmaf(xv.x, s, fmaf(-mu.x, s, bt.x));
        s   = g.y * rsqrtf(vr.y + EPSV); o.y = fmaf(xv.y, s, fmaf(-mu.y, s, bt.y));
        s   = g.z * rsqrtf(vr.z + EPSV); o.z = fmaf(xv.z, s, fmaf(-mu.z, s, bt.z));
        s   = g.w * rsqrtf(vr.w + EPSV); o.w = fmaf(xv.w, s, fmaf(-mu.w, s, bt.w));
    }
    out[idx] = o;
}

extern "C" void kernel_launch(void* const* d_in, const int* in_sizes, int n_in,
                              void* d_out, int out_size, void* d_ws, size_t ws_size,
                              hipStream_t stream) {
    const float* x     = (const float*)d_in[0];
    const float* mask  = (const float*)d_in[1];
    const float* gam   = (const float*)d_in[2];
    const float* bet   = (const float*)d_in[3];
    const float* mu    = (const float*)d_in[4];
    const float* var   = (const float*)d_in[5];
    float* out         = (float*)d_out;

    const int B = in_sizes[0] / F_DIM;  // 32768

    DomainBatchNorm_kernel<<<B, 256, 0, stream>>>(
        (const float4*)x, mask,
        (const float4*)gam, (const float4*)bet,
        (const float4*)mu,  (const float4*)var,
        (float4*)out);
}